// Round 4
// baseline (19300.519 us; speedup 1.0000x reference)
//
#include <hip/hip_runtime.h>

#define Bq 2
#define Sq 2048
#define Hq 16
#define Dq 64
#define QT 64            // queries per block (8 waves x 8)
#define KT 64            // keys per tile (double-buffered)
#define NT (Sq/KT)       // 32 tiles
#define HD (Hq*Dq)       // 1024

// async global->LDS, 16B/lane; LDS dest = wave-uniform base + lane*16
#define GLDS(g,l) __builtin_amdgcn_global_load_lds( \
    (const __attribute__((address_space(1))) void*)(g), \
    (__attribute__((address_space(3))) void*)(l), 16, 0, 0)
#define SBAR()   asm volatile("s_barrier" ::: "memory")
#define SCHED0() __builtin_amdgcn_sched_barrier(0)

// Flash-style, software-pipelined (T3/T4): K/V double-buffered in LDS,
// staging for tile t+1 issued a full tile early via global_load_lds and kept
// in flight ACROSS raw s_barriers with counted vmcnt (never drained to 0 in
// the loop). Bias/mask for tile t+1 load into regs during tile t's QK.
// P transposes through the dead current-K buffer (alias). 80 KB LDS.
__global__ __launch_bounds__(512) __attribute__((amdgpu_waves_per_eu(2, 4)))
void attn_fwd(const float* __restrict__ q,
              const float* __restrict__ k,
              const float* __restrict__ v,
              const float* __restrict__ bias,
              const int* __restrict__ mask,
              float* __restrict__ out)
{
  __shared__ float qs[QT*Dq];      // 16 KB
  __shared__ float ks[2][KT*Dq];   // 2 x 16 KB (K dbuf; cur half reused as P)
  __shared__ float vs[2][KT*Dq];   // 2 x 16 KB (V dbuf)

  const int tid  = threadIdx.x;
  const int lane = tid & 63;
  const int wv   = tid >> 6;

  // XCD-contiguous remap: consecutive logical blocks (same head) per XCD L2
  const int bid = (int)blockIdx.x;
  const int lid = ((bid & 7) << 7) | (bid >> 3);
  const int qt  = lid & 31;
  const int bh  = lid >> 5;
  const int h   = bh & (Hq - 1);
  const int b   = bh >> 4;
  const int q0  = qt * QT;
  const int qw  = q0 + wv*8;

  const float* qg = q + ((size_t)(b*Sq + q0)*Hq + h)*Dq;
  const float* kg = k + ((size_t)b*Sq*Hq + h)*Dq;
  const float* vg = v + ((size_t)b*Sq*Hq + h)*Dq;
  const float* bw = bias + ((size_t)((b*Hq + h)*Sq + qw))*Sq;
  const int*   mw = mask + ((size_t)(b*Sq + qw))*Sq;

  // ---- stage Q once (x8 = sqrt(D); reference MULTIPLIES q) ----
  #pragma unroll
  for (int r = 0; r < 2; ++r) {
    const int fo  = r*2048 + tid*4;
    const int row = fo >> 6, col = fo & 63;
    float4 t4 = *(const float4*)(qg + (size_t)row*HD + col);
    t4.x *= 8.f; t4.y *= 8.f; t4.z *= 8.f; t4.w *= 8.f;
    *(float4*)(&qs[fo]) = t4;
  }
  __syncthreads();   // only full drain in the kernel (before pipeline starts)

  float o[8][4];                 // 8 queries x 4-dim chunk (4-way key split)
  float m[8], l[8];
  float ba[8], bb_[8];           // bias double-buffer (regs)
  int   ma[8], mb_[8];           // mask double-buffer (regs)
  #pragma unroll
  for (int qi = 0; qi < 8; ++qi) {
    m[qi] = -3.0e38f; l[qi] = 0.f;
    #pragma unroll
    for (int d = 0; d < 4; ++d) o[qi][d] = 0.f;
  }

  const int swf = (lane & 7) << 2;       // K-row XOR swizzle (float units)
  const int g2  = lane >> 4;             // PV key subgroup 0..3
  const int cc  = lane & 15;             // PV dim chunk
  const int vr0 = g2*4 + 0, vr1 = g2*4 + 1, vr2 = g2*4 + 2, vr3 = g2*4 + 3;
  const int vof0 = vr0*64 + ((cc*4) ^ ((vr0 & 7) << 2));
  const int vof1 = vr1*64 + ((cc*4) ^ ((vr1 & 7) << 2));
  const int vof2 = vr2*64 + ((cc*4) ^ ((vr2 & 7) << 2));
  const int vof3 = vr3*64 + ((cc*4) ^ ((vr3 & 7) << 2));

  // stage K/V tile T into (bk,bv): 2 rounds x (K,V) = 4 gload_lds per thread
  auto stage = [&](int T, float* bk, float* bv) {
    const int j0 = T*KT;
    #pragma unroll
    for (int r = 0; r < 2; ++r) {
      const int fo  = r*2048 + tid*4;
      const int row = fo >> 6;
      const int col = (fo & 63) ^ ((row & 7) << 2);
      GLDS(kg + (size_t)(j0+row)*HD + col, bk + (r*2048 + wv*256));
      GLDS(vg + (size_t)(j0+row)*HD + col, bv + (r*2048 + wv*256));
    }
  };

  // ---- pipeline prologue: FIFO = [st0(4)][bm0(16)][st1(4)] ----
  SCHED0();
  stage(0, ks[0], vs[0]);
  SCHED0();
  { const float* bbp = bw + lane; const int* mmp = mw + lane;
    #pragma unroll
    for (int qi = 0; qi < 8; ++qi) {
      ba[qi] = bbp[(size_t)qi*Sq];
      ma[qi] = mmp[(size_t)qi*Sq];
    } }
  SCHED0();
  stage(1, ks[1], vs[1]);
  SCHED0();
  asm volatile("s_waitcnt vmcnt(20)" ::: "memory");  // st0 drained; bm0+st1 fly
  SBAR(); SCHED0();

// One tile. Entry invariant: tile T visible in KC/VC; st(T+1)(4) + bm(T)(regs,
// consumed via backend auto-wait) outstanding. Exit: st(T+2) issued into KC/VC.
#define BODY(T, KC, VC, BC, MC, BN, MN)                                       \
  {                                                                           \
    if ((T) + 1 < NT) {              /* issue bias/mask(T+1) -> regs */       \
      const float* bbp = bw + ((T)+1)*KT + lane;                              \
      const int*   mmp = mw + ((T)+1)*KT + lane;                              \
      _Pragma("unroll")                                                       \
      for (int qi = 0; qi < 8; ++qi) {                                        \
        BN[qi] = bbp[(size_t)qi*Sq];                                          \
        MN[qi] = mmp[(size_t)qi*Sq];                                          \
      }                                                                       \
    }                                                                         \
    SCHED0();                                                                 \
    float s[8];                                                               \
    _Pragma("unroll") for (int qi = 0; qi < 8; ++qi) s[qi] = 0.f;             \
    { const float* kr   = (KC) + lane*64;                                     \
      const float* qrow = &qs[wv*512];                                        \
      _Pragma("unroll")                                                       \
      for (int t4 = 0; t4 < 16; ++t4) {                                       \
        const float4 ka = *(const float4*)(kr + ((t4*4) ^ swf));              \
        _Pragma("unroll")                                                     \
        for (int qi = 0; qi < 8; ++qi) {                                      \
          const float4 qv = *(const float4*)(qrow + qi*64 + t4*4);            \
          s[qi] = fmaf(qv.x, ka.x, s[qi]);                                    \
          s[qi] = fmaf(qv.y, ka.y, s[qi]);                                    \
          s[qi] = fmaf(qv.z, ka.z, s[qi]);                                    \
          s[qi] = fmaf(qv.w, ka.w, s[qi]);                                    \
        }                                                                     \
      } }                                                                     \
    /* bias AFTER dot (same math) -> its loads hid under the FMAs */          \
    _Pragma("unroll")                                                         \
    for (int qi = 0; qi < 8; ++qi) {                                          \
      const float sv = s[qi] + BC[qi];                                        \
      s[qi] = (MC[qi] != 0) ? 0.0f : sv;  /* masked -> exact 0, NOT -inf */   \
    }                                                                         \
    _Pragma("unroll")                                                         \
    for (int qi = 0; qi < 8; ++qi) {                                          \
      float tm = s[qi];                                                       \
      _Pragma("unroll")                                                       \
      for (int off = 32; off; off >>= 1)                                      \
        tm = fmaxf(tm, __shfl_xor(tm, off, 64));                              \
      const float mn = fmaxf(m[qi], tm);                                      \
      const float p  = __expf(s[qi] - mn);                                    \
      float ls = p;                                                           \
      _Pragma("unroll")                                                       \
      for (int off = 32; off; off >>= 1) ls += __shfl_xor(ls, off, 64);       \
      if (mn != m[qi]) {               /* wave-uniform; skip *1.0 rescale */  \
        const float sc = __expf(m[qi] - mn);                                  \
        l[qi] = l[qi]*sc + ls; m[qi] = mn;                                    \
        _Pragma("unroll") for (int d = 0; d < 4; ++d) o[qi][d] *= sc;         \
      } else l[qi] += ls;                                                     \
      s[qi] = p;                                                              \
    }                                                                         \
    SBAR(); SCHED0();                  /* all QK reads of KC done */          \
    { float* pwl = (KC) + wv*512;      /* P aliases dead K tile */            \
      _Pragma("unroll")                                                       \
      for (int qi = 0; qi < 8; ++qi) pwl[qi*64 + lane] = s[qi];               \
      _Pragma("unroll")                                                       \
      for (int jj = 0; jj < 4; ++jj) {                                        \
        const float4 va = *(const float4*)((VC) + jj*1024 + vof0);            \
        const float4 vb = *(const float4*)((VC) + jj*1024 + vof1);            \
        const float4 vc = *(const float4*)((VC) + jj*1024 + vof2);            \
        const float4 vd = *(const float4*)((VC) + jj*1024 + vof3);            \
        _Pragma("unroll")                                                     \
        for (int qi = 0; qi < 8; ++qi) {                                      \
          const float4 pp = *(const float4*)(pwl + qi*64 + jj*16 + g2*4);     \
          o[qi][0] = fmaf(pp.x, va.x, o[qi][0]);                              \
          o[qi][1] = fmaf(pp.x, va.y, o[qi][1]);                              \
          o[qi][2] = fmaf(pp.x, va.z, o[qi][2]);                              \
          o[qi][3] = fmaf(pp.x, va.w, o[qi][3]);                              \
          o[qi][0] = fmaf(pp.y, vb.x, o[qi][0]);                              \
          o[qi][1] = fmaf(pp.y, vb.y, o[qi][1]);                              \
          o[qi][2] = fmaf(pp.y, vb.z, o[qi][2]);                              \
          o[qi][3] = fmaf(pp.y, vb.w, o[qi][3]);                              \
          o[qi][0] = fmaf(pp.z, vc.x, o[qi][0]);                              \
          o[qi][1] = fmaf(pp.z, vc.y, o[qi][1]);                              \
          o[qi][2] = fmaf(pp.z, vc.z, o[qi][2]);                              \
          o[qi][3] = fmaf(pp.z, vc.w, o[qi][3]);                              \
          o[qi][0] = fmaf(pp.w, vd.x, o[qi][0]);                              \
          o[qi][1] = fmaf(pp.w, vd.y, o[qi][1]);                              \
          o[qi][2] = fmaf(pp.w, vd.z, o[qi][2]);                              \
          o[qi][3] = fmaf(pp.w, vd.w, o[qi][3]);                              \
        }                                                                     \
      } }                                                                     \
    /* drain st(T+1) (4 oldest); keep bm(T+1) (16) in flight */               \
    asm volatile("s_waitcnt vmcnt(16)" ::: "memory");                         \
    SBAR(); SCHED0();                  /* tile T+1 visible; KC/VC free */     \
    if ((T) + 2 < NT) stage((T)+2, (KC), (VC));                               \
    SCHED0();                                                                 \
  }

  for (int t = 0; t < NT; t += 2) {
    BODY(t,   ks[0], vs[0], ba,  ma,  bb_, mb_);
    BODY(t+1, ks[1], vs[1], bb_, mb_, ba,  ma);
  }
#undef BODY

  // ---- reduce partials across the 4 key-subgroups ----
  #pragma unroll
  for (int qi = 0; qi < 8; ++qi) {
    #pragma unroll
    for (int d = 0; d < 4; ++d) {
      float t = o[qi][d];
      t += __shfl_xor(t, 16, 64);
      t += __shfl_xor(t, 32, 64);
      o[qi][d] = t;
    }
  }

  // lane (g2,cc) writes queries g2 and g2+4, dims cc*4..cc*4+3
  float la = l[0], lb = l[4];
  float oa[4], ob[4];
  #pragma unroll
  for (int d = 0; d < 4; ++d) { oa[d] = o[0][d]; ob[d] = o[4][d]; }
  #pragma unroll
  for (int ss = 1; ss < 4; ++ss) {
    const bool sel = (g2 == ss);
    la = sel ? l[ss]   : la;
    lb = sel ? l[ss+4] : lb;
    #pragma unroll
    for (int d = 0; d < 4; ++d) {
      oa[d] = sel ? o[ss][d]   : oa[d];
      ob[d] = sel ? o[ss+4][d] : ob[d];
    }
  }
  const float ra = 1.0f / la, rb = 1.0f / lb;

  float4 w4;
  w4.x = oa[0]*ra; w4.y = oa[1]*ra; w4.z = oa[2]*ra; w4.w = oa[3]*ra;
  *(float4*)(out + ((size_t)(b*Sq + qw + g2)*Hq + h)*Dq + cc*4) = w4;
  w4.x = ob[0]*rb; w4.y = ob[1]*rb; w4.z = ob[2]*rb; w4.w = ob[3]*rb;
  *(float4*)(out + ((size_t)(b*Sq + qw + g2 + 4)*Hq + h)*Dq + cc*4) = w4;
}

extern "C" void kernel_launch(void* const* d_in, const int* in_sizes, int n_in,
                              void* d_out, int out_size, void* d_ws, size_t ws_size,
                              hipStream_t stream)
{
  const float* q    = (const float*)d_in[0];
  const float* k    = (const float*)d_in[1];
  const float* v    = (const float*)d_in[2];
  const float* bias = (const float*)d_in[3];
  const int*   mask = (const int*)d_in[4];
  float*       out  = (float*)d_out;

  dim3 grid(Bq*Hq*(Sq/QT));   // 1024 blocks: (b,h) x 32 query-tiles
  attn_fwd<<<grid, dim3(512), 0, stream>>>(q, k, v, bias, mask, out);
}